// Round 1
// baseline (3234.090 us; speedup 1.0000x reference)
//
#include <hip/hip_runtime.h>
#include <math.h>

#define EPSF 1e-7f
#define YMAXF 0.99999f   // fp32(1 - 1e-5), same rounding as jnp clip constant

__device__ __forceinline__ float grp32_sum(float v) {
    // reduce within an aligned 32-lane group of the 64-lane wave
    v += __shfl_xor(v, 1);
    v += __shfl_xor(v, 2);
    v += __shfl_xor(v, 4);
    v += __shfl_xor(v, 8);
    v += __shfl_xor(v, 16);
    return v;
}

// Kernel 1: v = log_map_zero(x); agg = v (self contribution); count = 1
__global__ void logmap_kernel(const float* __restrict__ x,
                              const float* __restrict__ c_ptr,
                              float* __restrict__ v,
                              float* __restrict__ agg,
                              float* __restrict__ count,
                              int N) {
    int gid = blockIdx.x * blockDim.x + threadIdx.x;
    int row = gid >> 5;
    if (row >= N) return;
    int lane = gid & 31;
    const float4 xv = ((const float4*)x)[(size_t)row * 32 + lane];
    float ss = xv.x * xv.x + xv.y * xv.y + xv.z * xv.z + xv.w * xv.w;
    ss = grp32_sum(ss);
    float sc = sqrtf(c_ptr[0]);
    float xn = fmaxf(sqrtf(ss), EPSF);
    float y = fminf(sc * xn, YMAXF);
    float s = atanhf(y) / (sc * xn);
    float4 vv = make_float4(s * xv.x, s * xv.y, s * xv.z, s * xv.w);
    ((float4*)v)[(size_t)row * 32 + lane] = vv;
    ((float4*)agg)[(size_t)row * 32 + lane] = vv;
    if (lane == 0) count[row] = 1.0f;
}

// Kernel 2: agg[dst] += v[src]; count[dst] += 1   (32 lanes per edge, float4 each)
__global__ void edge_kernel(const float* __restrict__ v,
                            const int* __restrict__ eidx,
                            float* __restrict__ agg,
                            float* __restrict__ count,
                            int E) {
    int gid = blockIdx.x * blockDim.x + threadIdx.x;
    int e = gid >> 5;
    if (e >= E) return;
    int lane = gid & 31;
    int src = eidx[e];
    int dst = eidx[E + e];
    float4 vv = ((const float4*)v)[(size_t)src * 32 + lane];
    float* a = agg + (size_t)dst * 128 + lane * 4;
    unsafeAtomicAdd(a + 0, vv.x);
    unsafeAtomicAdd(a + 1, vv.y);
    unsafeAtomicAdd(a + 2, vv.z);
    unsafeAtomicAdd(a + 3, vv.w);
    if (lane == 0) unsafeAtomicAdd(count + dst, 1.0f);
}

// Kernel 3 (fused epilogue): v_agg = agg/count; exp->log map (norm chain);
// out = v2 @ W^T + bias; final = exp_map(out).
// 256 threads; 2 rows at a time (sub = tid>>7, o = tid&127); W^T staged in LDS
// with pitch 129 -> bank (k+o)%32, conflict-free reads.
__global__ __launch_bounds__(256)
void epilogue_kernel(const float* __restrict__ agg,
                     const float* __restrict__ count,
                     const float* __restrict__ W,
                     const float* __restrict__ bias,
                     const float* __restrict__ c_ptr,
                     float* __restrict__ out,
                     int N, int rows_per_block) {
    __shared__ float Wt[128 * 129];
    __shared__ float bias_s[128];
    __shared__ float v2row[2][128];
    __shared__ float red1[4];
    __shared__ float red2[4];

    int tid = threadIdx.x;
    for (int i = tid; i < 128 * 128; i += 256) {
        int o = i >> 7;
        int k = i & 127;
        Wt[k * 129 + o] = W[i];
    }
    if (tid < 128) bias_s[tid] = bias[tid];
    __syncthreads();

    float sc = sqrtf(c_ptr[0]);
    int sub = tid >> 7;
    int o = tid & 127;
    int row0 = blockIdx.x * rows_per_block;

    for (int r = 0; r < rows_per_block; r += 2) {
        int row = row0 + r + sub;
        bool valid = (row < N);
        float av = 0.0f, cnt = 1.0f;
        if (valid) {
            av = agg[(size_t)row * 128 + o];
            cnt = count[row];
        }
        float va = av / fmaxf(cnt, 1.0f);

        // row sumsq across 128 threads (2 waves) of this sub-row
        float ss = va * va;
        ss = grp32_sum(ss);
        ss += __shfl_xor(ss, 32);              // full 64-lane wave sum
        if ((tid & 63) == 0) red1[tid >> 6] = ss;
        __syncthreads();
        float vn = sqrtf(red1[sub * 2] + red1[sub * 2 + 1]);

        // exp_map_zero then log_map_zero
        float vnc = fmaxf(vn, EPSF);
        float th = tanhf(sc * vnc);
        float t = th / (sc * vnc);             // x_hyp = t * va
        float hn = fmaxf(th / sc, EPSF);       // ||x_hyp|| (clamped)
        float y2 = fminf(sc * hn, YMAXF);
        float s2 = atanhf(y2) / (sc * hn);     // v2 = s2 * x_hyp
        v2row[sub][o] = s2 * t * va;
        __syncthreads();

        // out_o = bias[o] + sum_k v2[k] * W[o][k]
        float acc = bias_s[o];
        #pragma unroll
        for (int k = 0; k < 128; ++k)
            acc = fmaf(v2row[sub][k], Wt[k * 129 + o], acc);

        // row norm of out
        float os = acc * acc;
        os = grp32_sum(os);
        os += __shfl_xor(os, 32);
        if ((tid & 63) == 0) red2[tid >> 6] = os;
        __syncthreads();
        float on = sqrtf(red2[sub * 2] + red2[sub * 2 + 1]);
        float onc = fmaxf(on, EPSF);
        float g = tanhf(sc * onc) / (sc * onc);

        if (valid) out[(size_t)row * 128 + o] = g * acc;
        __syncthreads();   // protect red1/red2/v2row reuse next iteration
    }
}

extern "C" void kernel_launch(void* const* d_in, const int* in_sizes, int n_in,
                              void* d_out, int out_size, void* d_ws, size_t ws_size,
                              hipStream_t stream) {
    const float* x     = (const float*)d_in[0];
    const int*   eidx  = (const int*)d_in[1];
    const float* c_ptr = (const float*)d_in[2];
    const float* W     = (const float*)d_in[4];
    const float* bias  = (const float*)d_in[5];
    float* out = (float*)d_out;

    int N = in_sizes[0] / 128;
    int E = in_sizes[1] / 2;

    float* v     = (float*)d_ws;
    float* agg   = v + (size_t)N * 128;
    float* count = agg + (size_t)N * 128;

    {
        long long threads = (long long)N * 32;
        int blocks = (int)((threads + 255) / 256);
        hipLaunchKernelGGL(logmap_kernel, dim3(blocks), dim3(256), 0, stream,
                           x, c_ptr, v, agg, count, N);
    }
    {
        long long threads = (long long)E * 32;
        int blocks = (int)((threads + 255) / 256);
        hipLaunchKernelGGL(edge_kernel, dim3(blocks), dim3(256), 0, stream,
                           v, eidx, agg, count, E);
    }
    {
        const int RPB = 64;
        int blocks = (N + RPB - 1) / RPB;
        hipLaunchKernelGGL(epilogue_kernel, dim3(blocks), dim3(256), 0, stream,
                           agg, count, W, bias, c_ptr, out, N, RPB);
    }
}

// Round 2
// 932.405 us; speedup vs baseline: 3.4685x; 3.4685x over previous
//
#include <hip/hip_runtime.h>
#include <math.h>

#define EPSF 1e-7f
#define YMAXF 0.99999f   // fp32(1 - 1e-5), same rounding as jnp clip constant

__device__ __forceinline__ float grp32_sum(float v) {
    v += __shfl_xor(v, 1);
    v += __shfl_xor(v, 2);
    v += __shfl_xor(v, 4);
    v += __shfl_xor(v, 8);
    v += __shfl_xor(v, 16);
    return v;
}

// Kernel 1: v = log_map_zero(x)
__global__ void logmap_kernel(const float* __restrict__ x,
                              const float* __restrict__ c_ptr,
                              float* __restrict__ v,
                              int N) {
    int gid = blockIdx.x * blockDim.x + threadIdx.x;
    int row = gid >> 5;
    if (row >= N) return;
    int lane = gid & 31;
    const float4 xv = ((const float4*)x)[(size_t)row * 32 + lane];
    float ss = xv.x * xv.x + xv.y * xv.y + xv.z * xv.z + xv.w * xv.w;
    ss = grp32_sum(ss);
    float sc = sqrtf(c_ptr[0]);
    float xn = fmaxf(sqrtf(ss), EPSF);
    float y = fminf(sc * xn, YMAXF);
    float s = atanhf(y) / (sc * xn);
    ((float4*)v)[(size_t)row * 32 + lane] =
        make_float4(s * xv.x, s * xv.y, s * xv.z, s * xv.w);
}

// Kernel 2: in-degree histogram
__global__ void hist_kernel(const int* __restrict__ eidx, int* __restrict__ deg, int E) {
    int e = blockIdx.x * blockDim.x + threadIdx.x;
    if (e >= E) return;
    atomicAdd(&deg[eidx[E + e]], 1);
}

// Kernel 3: single-block exclusive scan of deg -> offsets (1024 threads)
__global__ __launch_bounds__(1024)
void scan_kernel(const int* __restrict__ deg, int* __restrict__ offsets, int N) {
    __shared__ int part[1024];
    int tid = threadIdx.x;
    int chunk = (N + 1023) / 1024;
    int start = tid * chunk;
    int end = min(start + chunk, N);
    int s = 0;
    for (int i = start; i < end; ++i) s += deg[i];
    part[tid] = s;
    __syncthreads();
    // Hillis-Steele inclusive scan
    for (int off = 1; off < 1024; off <<= 1) {
        int val = (tid >= off) ? part[tid - off] : 0;
        __syncthreads();
        part[tid] += val;
        __syncthreads();
    }
    int run = (tid == 0) ? 0 : part[tid - 1];
    for (int i = start; i < end; ++i) {
        offsets[i] = run;
        run += deg[i];
    }
}

// Kernel 4: scatter edges into dst-sorted order. offsets[] is consumed as a
// cursor: after this kernel offsets[d] == end of segment d (start = end - deg[d]).
__global__ void scatter_kernel(const int* __restrict__ eidx, int* __restrict__ offsets,
                               int* __restrict__ sorted_src, int E) {
    int e = blockIdx.x * blockDim.x + threadIdx.x;
    if (e >= E) return;
    int dst = eidx[E + e];
    int pos = atomicAdd(&offsets[dst], 1);
    sorted_src[pos] = eidx[e];
}

// Kernel 5: gather-reduce. 32-lane group per dst row, float4 per lane.
// v_agg[row] = (v[row] + sum_{src in N(row)} v[src]) / (deg+1)
__global__ void gather_kernel(const float* __restrict__ v,
                              const int* __restrict__ sorted_src,
                              const int* __restrict__ offsets_post,
                              const int* __restrict__ deg,
                              float* __restrict__ v_agg,
                              int N) {
    int gid = blockIdx.x * blockDim.x + threadIdx.x;
    int row = gid >> 5;
    if (row >= N) return;
    int lane = gid & 31;
    int end = offsets_post[row];
    int d = deg[row];
    int start = end - d;
    const float4* vp = (const float4*)v;
    float4 acc = vp[(size_t)row * 32 + lane];   // self contribution
    int j = start;
    for (; j + 2 <= end; j += 2) {
        int s0 = sorted_src[j];
        int s1 = sorted_src[j + 1];
        float4 a = vp[(size_t)s0 * 32 + lane];
        float4 b = vp[(size_t)s1 * 32 + lane];
        acc.x += a.x + b.x;
        acc.y += a.y + b.y;
        acc.z += a.z + b.z;
        acc.w += a.w + b.w;
    }
    if (j < end) {
        float4 a = vp[(size_t)sorted_src[j] * 32 + lane];
        acc.x += a.x; acc.y += a.y; acc.z += a.z; acc.w += a.w;
    }
    float inv = 1.0f / (float)(d + 1);
    ((float4*)v_agg)[(size_t)row * 32 + lane] =
        make_float4(acc.x * inv, acc.y * inv, acc.z * inv, acc.w * inv);
}

// Kernel 6 (epilogue): exp->log map chain; out = v2 @ W^T + bias; exp_map(out).
__global__ __launch_bounds__(256)
void epilogue_kernel(const float* __restrict__ v_agg,
                     const float* __restrict__ W,
                     const float* __restrict__ bias,
                     const float* __restrict__ c_ptr,
                     float* __restrict__ out,
                     int N, int rows_per_block) {
    __shared__ float Wt[128 * 129];
    __shared__ float bias_s[128];
    __shared__ float v2row[2][128];
    __shared__ float red1[4];
    __shared__ float red2[4];

    int tid = threadIdx.x;
    for (int i = tid; i < 128 * 128; i += 256) {
        int o = i >> 7;
        int k = i & 127;
        Wt[k * 129 + o] = W[i];
    }
    if (tid < 128) bias_s[tid] = bias[tid];
    __syncthreads();

    float sc = sqrtf(c_ptr[0]);
    int sub = tid >> 7;
    int o = tid & 127;
    int row0 = blockIdx.x * rows_per_block;

    for (int r = 0; r < rows_per_block; r += 2) {
        int row = row0 + r + sub;
        bool valid = (row < N);
        float va = valid ? v_agg[(size_t)row * 128 + o] : 0.0f;

        float ss = va * va;
        ss = grp32_sum(ss);
        ss += __shfl_xor(ss, 32);
        if ((tid & 63) == 0) red1[tid >> 6] = ss;
        __syncthreads();
        float vn = sqrtf(red1[sub * 2] + red1[sub * 2 + 1]);

        float vnc = fmaxf(vn, EPSF);
        float th = tanhf(sc * vnc);
        float t = th / (sc * vnc);             // x_hyp = t * va
        float hn = fmaxf(th / sc, EPSF);       // ||x_hyp||
        float y2 = fminf(sc * hn, YMAXF);
        float s2 = atanhf(y2) / (sc * hn);     // v2 = s2 * x_hyp
        v2row[sub][o] = s2 * t * va;
        __syncthreads();

        float acc = bias_s[o];
        #pragma unroll
        for (int k = 0; k < 128; ++k)
            acc = fmaf(v2row[sub][k], Wt[k * 129 + o], acc);

        float os = acc * acc;
        os = grp32_sum(os);
        os += __shfl_xor(os, 32);
        if ((tid & 63) == 0) red2[tid >> 6] = os;
        __syncthreads();
        float on = sqrtf(red2[sub * 2] + red2[sub * 2 + 1]);
        float onc = fmaxf(on, EPSF);
        float g = tanhf(sc * onc) / (sc * onc);

        if (valid) out[(size_t)row * 128 + o] = g * acc;
        __syncthreads();
    }
}

extern "C" void kernel_launch(void* const* d_in, const int* in_sizes, int n_in,
                              void* d_out, int out_size, void* d_ws, size_t ws_size,
                              hipStream_t stream) {
    const float* x     = (const float*)d_in[0];
    const int*   eidx  = (const int*)d_in[1];
    const float* c_ptr = (const float*)d_in[2];
    const float* W     = (const float*)d_in[4];
    const float* bias  = (const float*)d_in[5];
    float* out = (float*)d_out;

    int N = in_sizes[0] / 128;
    int E = in_sizes[1] / 2;

    float* v       = (float*)d_ws;                    // N*128 floats
    float* v_agg   = v + (size_t)N * 128;             // N*128 floats
    int*   deg     = (int*)(v_agg + (size_t)N * 128); // N ints
    int*   offsets = deg + N;                         // N ints (becomes cursor)
    int*   sorted_src = offsets + N;                  // E ints

    hipMemsetAsync(deg, 0, (size_t)N * sizeof(int), stream);

    {
        long long threads = (long long)N * 32;
        int blocks = (int)((threads + 255) / 256);
        hipLaunchKernelGGL(logmap_kernel, dim3(blocks), dim3(256), 0, stream,
                           x, c_ptr, v, N);
    }
    {
        int blocks = (E + 255) / 256;
        hipLaunchKernelGGL(hist_kernel, dim3(blocks), dim3(256), 0, stream,
                           eidx, deg, E);
    }
    hipLaunchKernelGGL(scan_kernel, dim3(1), dim3(1024), 0, stream, deg, offsets, N);
    {
        int blocks = (E + 255) / 256;
        hipLaunchKernelGGL(scatter_kernel, dim3(blocks), dim3(256), 0, stream,
                           eidx, offsets, sorted_src, E);
    }
    {
        long long threads = (long long)N * 32;
        int blocks = (int)((threads + 255) / 256);
        hipLaunchKernelGGL(gather_kernel, dim3(blocks), dim3(256), 0, stream,
                           v, sorted_src, offsets, deg, v_agg, N);
    }
    {
        const int RPB = 64;
        int blocks = (N + RPB - 1) / RPB;
        hipLaunchKernelGGL(epilogue_kernel, dim3(blocks), dim3(256), 0, stream,
                           v_agg, W, bias, c_ptr, out, N, RPB);
    }
}

// Round 3
// 623.943 us; speedup vs baseline: 5.1833x; 1.4944x over previous
//
#include <hip/hip_runtime.h>
#include <math.h>

#define EPSF 1e-7f
#define YMAXF 0.99999f   // fp32(1 - 1e-5), same rounding as jnp clip constant
#define WPITCH 136       // bf16 pitch: 272 B/row -> start bank 4*row%32, <=2-way (free)

typedef short bf16x8 __attribute__((ext_vector_type(8)));
typedef short bf16x4 __attribute__((ext_vector_type(4)));
typedef float f32x4  __attribute__((ext_vector_type(4)));

__device__ __forceinline__ float grp32_sum(float v) {
    v += __shfl_xor(v, 1);
    v += __shfl_xor(v, 2);
    v += __shfl_xor(v, 4);
    v += __shfl_xor(v, 8);
    v += __shfl_xor(v, 16);
    return v;
}

__device__ __forceinline__ short f2bf(float f) {
    // round-to-nearest-even fp32 -> bf16
    unsigned u = __float_as_uint(f);
    unsigned r = (u + 0x7FFFu + ((u >> 16) & 1u)) >> 16;
    return (short)r;
}

// Kernel 1: v = log_map_zero(x)
__global__ void logmap_kernel(const float* __restrict__ x,
                              const float* __restrict__ c_ptr,
                              float* __restrict__ v,
                              int N) {
    int gid = blockIdx.x * blockDim.x + threadIdx.x;
    int row = gid >> 5;
    if (row >= N) return;
    int lane = gid & 31;
    const float4 xv = ((const float4*)x)[(size_t)row * 32 + lane];
    float ss = xv.x * xv.x + xv.y * xv.y + xv.z * xv.z + xv.w * xv.w;
    ss = grp32_sum(ss);
    float sc = sqrtf(c_ptr[0]);
    float xn = fmaxf(sqrtf(ss), EPSF);
    float y = fminf(sc * xn, YMAXF);
    float s = atanhf(y) / (sc * xn);
    ((float4*)v)[(size_t)row * 32 + lane] =
        make_float4(s * xv.x, s * xv.y, s * xv.z, s * xv.w);
}

// Kernel 2: in-degree histogram
__global__ void hist_kernel(const int* __restrict__ eidx, int* __restrict__ deg, int E) {
    int e = blockIdx.x * blockDim.x + threadIdx.x;
    if (e >= E) return;
    atomicAdd(&deg[eidx[E + e]], 1);
}

// Kernel 3: single-block exclusive scan of deg -> offsets (1024 threads)
__global__ __launch_bounds__(1024)
void scan_kernel(const int* __restrict__ deg, int* __restrict__ offsets, int N) {
    __shared__ int part[1024];
    int tid = threadIdx.x;
    int chunk = (N + 1023) / 1024;
    int start = tid * chunk;
    int end = min(start + chunk, N);
    int s = 0;
    for (int i = start; i < end; ++i) s += deg[i];
    part[tid] = s;
    __syncthreads();
    for (int off = 1; off < 1024; off <<= 1) {
        int val = (tid >= off) ? part[tid - off] : 0;
        __syncthreads();
        part[tid] += val;
        __syncthreads();
    }
    int run = (tid == 0) ? 0 : part[tid - 1];
    for (int i = start; i < end; ++i) {
        offsets[i] = run;
        run += deg[i];
    }
}

// Kernel 4: scatter edges into dst-sorted order (offsets becomes end-cursor)
__global__ void scatter_kernel(const int* __restrict__ eidx, int* __restrict__ offsets,
                               int* __restrict__ sorted_src, int E) {
    int e = blockIdx.x * blockDim.x + threadIdx.x;
    if (e >= E) return;
    int dst = eidx[E + e];
    int pos = atomicAdd(&offsets[dst], 1);
    sorted_src[pos] = eidx[e];
}

// Kernel 5: gather-reduce. 32-lane group per dst row, float4 per lane.
__global__ void gather_kernel(const float* __restrict__ v,
                              const int* __restrict__ sorted_src,
                              const int* __restrict__ offsets_post,
                              const int* __restrict__ deg,
                              float* __restrict__ v_agg,
                              int N) {
    int gid = blockIdx.x * blockDim.x + threadIdx.x;
    int row = gid >> 5;
    if (row >= N) return;
    int lane = gid & 31;
    int end = offsets_post[row];
    int d = deg[row];
    int start = end - d;
    const float4* vp = (const float4*)v;
    float4 acc = vp[(size_t)row * 32 + lane];
    int j = start;
    for (; j + 2 <= end; j += 2) {
        int s0 = sorted_src[j];
        int s1 = sorted_src[j + 1];
        float4 a = vp[(size_t)s0 * 32 + lane];
        float4 b = vp[(size_t)s1 * 32 + lane];
        acc.x += a.x + b.x;
        acc.y += a.y + b.y;
        acc.z += a.z + b.z;
        acc.w += a.w + b.w;
    }
    if (j < end) {
        float4 a = vp[(size_t)sorted_src[j] * 32 + lane];
        acc.x += a.x; acc.y += a.y; acc.z += a.z; acc.w += a.w;
    }
    float inv = 1.0f / (float)(d + 1);
    ((float4*)v_agg)[(size_t)row * 32 + lane] =
        make_float4(acc.x * inv, acc.y * inv, acc.z * inv, acc.w * inv);
}

// Kernel 6 (MFMA epilogue): per 16-row tile:
//   fp32 row-norm -> exp/log map scale -> v2 (bf16, LDS A-frags)
//   out = v2 @ W^T + bias via mfma_f32_16x16x32_bf16 (fp32 accum, bias-init)
//   fp32 out row-norm -> exp_map scale -> store
// 4 waves x 2 col-tiles of 16. W staged once/block as bf16 (B-operand order).
__global__ __launch_bounds__(256)
void epilogue_mfma_kernel(const float* __restrict__ v_agg,
                          const float* __restrict__ W,
                          const float* __restrict__ bias,
                          const float* __restrict__ c_ptr,
                          float* __restrict__ out,
                          int N, int tiles_per_block) {
    __shared__ short Wl[128 * WPITCH];   // [o][k] bf16
    __shared__ short v2l[16 * WPITCH];   // [row][k] bf16
    __shared__ float bias_s[128];
    __shared__ float ssrow[16];
    __shared__ float scale_s[16];
    __shared__ float outss[16][4];
    __shared__ float gscale[16];

    int tid = threadIdx.x;
    for (int i = tid; i < 4096; i += 256) {       // float4 index over W
        float4 w4 = ((const float4*)W)[i];
        int o = i >> 5;
        int k = (i & 31) * 4;
        bf16x4 w;
        w[0] = f2bf(w4.x); w[1] = f2bf(w4.y); w[2] = f2bf(w4.z); w[3] = f2bf(w4.w);
        *(bf16x4*)&Wl[o * WPITCH + k] = w;
    }
    if (tid < 128) bias_s[tid] = bias[tid];
    float sc = sqrtf(c_ptr[0]);
    __syncthreads();

    int wave = tid >> 6;
    int lane = tid & 63;
    int quad = lane >> 4;
    int l16  = lane & 15;
    int rowA = tid >> 5;          // 0..7 (row 8..15 via +8)
    int colA = (tid & 31) * 4;
    int n0 = wave * 32;
    float b0 = bias_s[n0 + l16];
    float b1 = bias_s[n0 + 16 + l16];

    for (int t = 0; t < tiles_per_block; ++t) {
        int tile = blockIdx.x * tiles_per_block + t;
        int row0 = tile * 16;
        if (row0 >= N) break;      // N % 16 == 0 here, tiles are always full

        const float4* vp = (const float4*)v_agg + (size_t)row0 * 32;
        float4 a4 = vp[tid];
        float4 c4 = vp[tid + 256];
        float ssa = a4.x*a4.x + a4.y*a4.y + a4.z*a4.z + a4.w*a4.w;
        float ssb = c4.x*c4.x + c4.y*c4.y + c4.z*c4.z + c4.w*c4.w;
        ssa = grp32_sum(ssa);
        ssb = grp32_sum(ssb);
        if ((tid & 31) == 0) { ssrow[rowA] = ssa; ssrow[rowA + 8] = ssb; }
        __syncthreads();
        if (tid < 16) {
            float vn  = sqrtf(ssrow[tid]);
            float vnc = fmaxf(vn, EPSF);
            float th  = tanhf(sc * vnc);
            float tt  = th / (sc * vnc);          // x_hyp = tt * v_agg
            float hn  = fmaxf(th / sc, EPSF);
            float y2  = fminf(sc * hn, YMAXF);
            float s2  = atanhf(y2) / (sc * hn);   // v2 = s2 * x_hyp
            scale_s[tid] = s2 * tt;
        }
        __syncthreads();
        float sa = scale_s[rowA], sb = scale_s[rowA + 8];
        bf16x4 va, vb;
        va[0]=f2bf(a4.x*sa); va[1]=f2bf(a4.y*sa); va[2]=f2bf(a4.z*sa); va[3]=f2bf(a4.w*sa);
        vb[0]=f2bf(c4.x*sb); vb[1]=f2bf(c4.y*sb); vb[2]=f2bf(c4.z*sb); vb[3]=f2bf(c4.w*sb);
        *(bf16x4*)&v2l[rowA * WPITCH + colA] = va;
        *(bf16x4*)&v2l[(rowA + 8) * WPITCH + colA] = vb;
        __syncthreads();

        f32x4 acc0 = {b0, b0, b0, b0};
        f32x4 acc1 = {b1, b1, b1, b1};
        #pragma unroll
        for (int k0 = 0; k0 < 128; k0 += 32) {
            bf16x8 af  = *(const bf16x8*)&v2l[l16 * WPITCH + k0 + quad * 8];
            bf16x8 bf0 = *(const bf16x8*)&Wl[(n0 + l16) * WPITCH + k0 + quad * 8];
            bf16x8 bf1 = *(const bf16x8*)&Wl[(n0 + 16 + l16) * WPITCH + k0 + quad * 8];
            acc0 = __builtin_amdgcn_mfma_f32_16x16x32_bf16(af, bf0, acc0, 0, 0, 0);
            acc1 = __builtin_amdgcn_mfma_f32_16x16x32_bf16(af, bf1, acc1, 0, 0, 0);
        }

        // out row sumsq: D(row=quad*4+reg, col=l16); reduce over the 16 lanes of
        // this quad, then across waves via LDS
        float pss[4];
        #pragma unroll
        for (int r = 0; r < 4; ++r) {
            float vsum = acc0[r]*acc0[r] + acc1[r]*acc1[r];
            vsum += __shfl_xor(vsum, 1);
            vsum += __shfl_xor(vsum, 2);
            vsum += __shfl_xor(vsum, 4);
            vsum += __shfl_xor(vsum, 8);
            pss[r] = vsum;
        }
        if (l16 == 0) {
            #pragma unroll
            for (int r = 0; r < 4; ++r) outss[quad * 4 + r][wave] = pss[r];
        }
        __syncthreads();
        if (tid < 16) {
            float on  = sqrtf(outss[tid][0] + outss[tid][1] + outss[tid][2] + outss[tid][3]);
            float onc = fmaxf(on, EPSF);
            gscale[tid] = tanhf(sc * onc) / (sc * onc);
        }
        __syncthreads();
        #pragma unroll
        for (int r = 0; r < 4; ++r) {
            int row = quad * 4 + r;
            float g = gscale[row];
            size_t base = (size_t)(row0 + row) * 128;
            out[base + n0 + l16]      = g * acc0[r];
            out[base + n0 + 16 + l16] = g * acc1[r];
        }
        __syncthreads();   // protect ssrow/scale_s/v2l/outss/gscale next iter
    }
}

extern "C" void kernel_launch(void* const* d_in, const int* in_sizes, int n_in,
                              void* d_out, int out_size, void* d_ws, size_t ws_size,
                              hipStream_t stream) {
    const float* x     = (const float*)d_in[0];
    const int*   eidx  = (const int*)d_in[1];
    const float* c_ptr = (const float*)d_in[2];
    const float* W     = (const float*)d_in[4];
    const float* bias  = (const float*)d_in[5];
    float* out = (float*)d_out;

    int N = in_sizes[0] / 128;
    int E = in_sizes[1] / 2;

    float* v       = (float*)d_ws;                    // N*128 floats
    float* v_agg   = v + (size_t)N * 128;             // N*128 floats
    int*   deg     = (int*)(v_agg + (size_t)N * 128); // N ints
    int*   offsets = deg + N;                         // N ints (becomes cursor)
    int*   sorted_src = offsets + N;                  // E ints

    hipMemsetAsync(deg, 0, (size_t)N * sizeof(int), stream);

    {
        long long threads = (long long)N * 32;
        int blocks = (int)((threads + 255) / 256);
        hipLaunchKernelGGL(logmap_kernel, dim3(blocks), dim3(256), 0, stream,
                           x, c_ptr, v, N);
    }
    {
        int blocks = (E + 255) / 256;
        hipLaunchKernelGGL(hist_kernel, dim3(blocks), dim3(256), 0, stream,
                           eidx, deg, E);
    }
    hipLaunchKernelGGL(scan_kernel, dim3(1), dim3(1024), 0, stream, deg, offsets, N);
    {
        int blocks = (E + 255) / 256;
        hipLaunchKernelGGL(scatter_kernel, dim3(blocks), dim3(256), 0, stream,
                           eidx, offsets, sorted_src, E);
    }
    {
        long long threads = (long long)N * 32;
        int blocks = (int)((threads + 255) / 256);
        hipLaunchKernelGGL(gather_kernel, dim3(blocks), dim3(256), 0, stream,
                           v, sorted_src, offsets, deg, v_agg, N);
    }
    {
        const int TPB = 5;                       // 16-row tiles per block
        int numTiles = (N + 15) / 16;
        int blocks = (numTiles + TPB - 1) / TPB; // 1250 blocks for N=100k
        hipLaunchKernelGGL(epilogue_mfma_kernel, dim3(blocks), dim3(256), 0, stream,
                           v_agg, W, bias, c_ptr, out, N, TPB);
    }
}

// Round 4
// 434.426 us; speedup vs baseline: 7.4445x; 1.4362x over previous
//
#include <hip/hip_runtime.h>
#include <math.h>

#define EPSF 1e-7f
#define YMAXF 0.99999f   // fp32(1 - 1e-5), same rounding as jnp clip constant
#define WPITCH 136       // bf16 pitch: 272 B/row -> start bank 4*row%32, <=2-way (free)

#define SCAN_BLOCKS 200  // 200 blocks * 256 thr * 2 elems = 102400 >= N

typedef short bf16x8 __attribute__((ext_vector_type(8)));
typedef short bf16x4 __attribute__((ext_vector_type(4)));
typedef float f32x4  __attribute__((ext_vector_type(4)));

__device__ __forceinline__ float grp32_sum(float v) {
    v += __shfl_xor(v, 1);
    v += __shfl_xor(v, 2);
    v += __shfl_xor(v, 4);
    v += __shfl_xor(v, 8);
    v += __shfl_xor(v, 16);
    return v;
}

__device__ __forceinline__ short f2bf(float f) {
    unsigned u = __float_as_uint(f);
    unsigned r = (u + 0x7FFFu + ((u >> 16) & 1u)) >> 16;
    return (short)r;
}

// Kernel 1: v = log_map_zero(x)
__global__ void logmap_kernel(const float* __restrict__ x,
                              const float* __restrict__ c_ptr,
                              float* __restrict__ v,
                              int N) {
    int gid = blockIdx.x * blockDim.x + threadIdx.x;
    int row = gid >> 5;
    if (row >= N) return;
    int lane = gid & 31;
    const float4 xv = ((const float4*)x)[(size_t)row * 32 + lane];
    float ss = xv.x * xv.x + xv.y * xv.y + xv.z * xv.z + xv.w * xv.w;
    ss = grp32_sum(ss);
    float sc = sqrtf(c_ptr[0]);
    float xn = fmaxf(sqrtf(ss), EPSF);
    float y = fminf(sc * xn, YMAXF);
    float s = atanhf(y) / (sc * xn);
    ((float4*)v)[(size_t)row * 32 + lane] =
        make_float4(s * xv.x, s * xv.y, s * xv.z, s * xv.w);
}

// Kernel 2: in-degree histogram
__global__ void hist_kernel(const int* __restrict__ eidx, int* __restrict__ deg, int E) {
    int e = blockIdx.x * blockDim.x + threadIdx.x;
    if (e >= E) return;
    atomicAdd(&deg[eidx[E + e]], 1);
}

// ---- 3-pass hierarchical exclusive scan of deg[N] -> offsets[N] ----
// Pass 1: per-block sums (each block covers 512 elements)
__global__ __launch_bounds__(256)
void scan_pass1(const int* __restrict__ deg, int* __restrict__ blocksums, int N) {
    __shared__ int wsum[4];
    int tid = threadIdx.x;
    int i = (blockIdx.x * 256 + tid) * 2;
    int d0 = (i < N) ? deg[i] : 0;
    int d1 = (i + 1 < N) ? deg[i + 1] : 0;
    int s = d0 + d1;
    #pragma unroll
    for (int off = 1; off < 64; off <<= 1) s += __shfl_xor(s, off);
    if ((tid & 63) == 0) wsum[tid >> 6] = s;
    __syncthreads();
    if (tid == 0) blocksums[blockIdx.x] = wsum[0] + wsum[1] + wsum[2] + wsum[3];
}

// Pass 2: scan the block sums (single 256-thread block; SCAN_BLOCKS <= 256)
__global__ __launch_bounds__(256)
void scan_pass2(int* __restrict__ blocksums, int nb) {
    __shared__ int part[256];
    int tid = threadIdx.x;
    int val = (tid < nb) ? blocksums[tid] : 0;
    part[tid] = val;
    __syncthreads();
    for (int off = 1; off < 256; off <<= 1) {
        int t = (tid >= off) ? part[tid - off] : 0;
        __syncthreads();
        part[tid] += t;
        __syncthreads();
    }
    if (tid < nb) blocksums[tid] = (tid == 0) ? 0 : part[tid - 1];  // exclusive
}

// Pass 3: in-block exclusive scan + add block offset -> final offsets
__global__ __launch_bounds__(256)
void scan_pass3(const int* __restrict__ deg, const int* __restrict__ blocksums,
                int* __restrict__ offsets, int N) {
    __shared__ int part[256];
    int tid = threadIdx.x;
    int i = (blockIdx.x * 256 + tid) * 2;
    int d0 = (i < N) ? deg[i] : 0;
    int d1 = (i + 1 < N) ? deg[i + 1] : 0;
    part[tid] = d0 + d1;
    __syncthreads();
    for (int off = 1; off < 256; off <<= 1) {
        int t = (tid >= off) ? part[tid - off] : 0;
        __syncthreads();
        part[tid] += t;
        __syncthreads();
    }
    int base = blocksums[blockIdx.x] + ((tid == 0) ? 0 : part[tid - 1]);
    if (i < N) offsets[i] = base;
    if (i + 1 < N) offsets[i + 1] = base + d0;
}

// Kernel 4: scatter edges into dst-sorted order (offsets becomes end-cursor)
__global__ void scatter_kernel(const int* __restrict__ eidx, int* __restrict__ offsets,
                               int* __restrict__ sorted_src, int E) {
    int e = blockIdx.x * blockDim.x + threadIdx.x;
    if (e >= E) return;
    int dst = eidx[E + e];
    int pos = atomicAdd(&offsets[dst], 1);
    sorted_src[pos] = eidx[e];
}

// Kernel 5: gather-reduce. 32-lane group per dst row, float4 per lane.
__global__ void gather_kernel(const float* __restrict__ v,
                              const int* __restrict__ sorted_src,
                              const int* __restrict__ offsets_post,
                              const int* __restrict__ deg,
                              float* __restrict__ v_agg,
                              int N) {
    int gid = blockIdx.x * blockDim.x + threadIdx.x;
    int row = gid >> 5;
    if (row >= N) return;
    int lane = gid & 31;
    int end = offsets_post[row];
    int d = deg[row];
    int start = end - d;
    const float4* vp = (const float4*)v;
    float4 acc = vp[(size_t)row * 32 + lane];
    int j = start;
    for (; j + 2 <= end; j += 2) {
        int s0 = sorted_src[j];
        int s1 = sorted_src[j + 1];
        float4 a = vp[(size_t)s0 * 32 + lane];
        float4 b = vp[(size_t)s1 * 32 + lane];
        acc.x += a.x + b.x;
        acc.y += a.y + b.y;
        acc.z += a.z + b.z;
        acc.w += a.w + b.w;
    }
    if (j < end) {
        float4 a = vp[(size_t)sorted_src[j] * 32 + lane];
        acc.x += a.x; acc.y += a.y; acc.z += a.z; acc.w += a.w;
    }
    float inv = 1.0f / (float)(d + 1);
    ((float4*)v_agg)[(size_t)row * 32 + lane] =
        make_float4(acc.x * inv, acc.y * inv, acc.z * inv, acc.w * inv);
}

// Kernel 6 (MFMA epilogue) — unchanged from round 3
__global__ __launch_bounds__(256)
void epilogue_mfma_kernel(const float* __restrict__ v_agg,
                          const float* __restrict__ W,
                          const float* __restrict__ bias,
                          const float* __restrict__ c_ptr,
                          float* __restrict__ out,
                          int N, int tiles_per_block) {
    __shared__ short Wl[128 * WPITCH];
    __shared__ short v2l[16 * WPITCH];
    __shared__ float bias_s[128];
    __shared__ float ssrow[16];
    __shared__ float scale_s[16];
    __shared__ float outss[16][4];
    __shared__ float gscale[16];

    int tid = threadIdx.x;
    for (int i = tid; i < 4096; i += 256) {
        float4 w4 = ((const float4*)W)[i];
        int o = i >> 5;
        int k = (i & 31) * 4;
        bf16x4 w;
        w[0] = f2bf(w4.x); w[1] = f2bf(w4.y); w[2] = f2bf(w4.z); w[3] = f2bf(w4.w);
        *(bf16x4*)&Wl[o * WPITCH + k] = w;
    }
    if (tid < 128) bias_s[tid] = bias[tid];
    float sc = sqrtf(c_ptr[0]);
    __syncthreads();

    int wave = tid >> 6;
    int lane = tid & 63;
    int quad = lane >> 4;
    int l16  = lane & 15;
    int rowA = tid >> 5;
    int colA = (tid & 31) * 4;
    int n0 = wave * 32;
    float b0 = bias_s[n0 + l16];
    float b1 = bias_s[n0 + 16 + l16];

    for (int t = 0; t < tiles_per_block; ++t) {
        int tile = blockIdx.x * tiles_per_block + t;
        int row0 = tile * 16;
        if (row0 >= N) break;

        const float4* vp = (const float4*)v_agg + (size_t)row0 * 32;
        float4 a4 = vp[tid];
        float4 c4 = vp[tid + 256];
        float ssa = a4.x*a4.x + a4.y*a4.y + a4.z*a4.z + a4.w*a4.w;
        float ssb = c4.x*c4.x + c4.y*c4.y + c4.z*c4.z + c4.w*c4.w;
        ssa = grp32_sum(ssa);
        ssb = grp32_sum(ssb);
        if ((tid & 31) == 0) { ssrow[rowA] = ssa; ssrow[rowA + 8] = ssb; }
        __syncthreads();
        if (tid < 16) {
            float vn  = sqrtf(ssrow[tid]);
            float vnc = fmaxf(vn, EPSF);
            float th  = tanhf(sc * vnc);
            float tt  = th / (sc * vnc);
            float hn  = fmaxf(th / sc, EPSF);
            float y2  = fminf(sc * hn, YMAXF);
            float s2  = atanhf(y2) / (sc * hn);
            scale_s[tid] = s2 * tt;
        }
        __syncthreads();
        float sa = scale_s[rowA], sb = scale_s[rowA + 8];
        bf16x4 va, vb;
        va[0]=f2bf(a4.x*sa); va[1]=f2bf(a4.y*sa); va[2]=f2bf(a4.z*sa); va[3]=f2bf(a4.w*sa);
        vb[0]=f2bf(c4.x*sb); vb[1]=f2bf(c4.y*sb); vb[2]=f2bf(c4.z*sb); vb[3]=f2bf(c4.w*sb);
        *(bf16x4*)&v2l[rowA * WPITCH + colA] = va;
        *(bf16x4*)&v2l[(rowA + 8) * WPITCH + colA] = vb;
        __syncthreads();

        f32x4 acc0 = {b0, b0, b0, b0};
        f32x4 acc1 = {b1, b1, b1, b1};
        #pragma unroll
        for (int k0 = 0; k0 < 128; k0 += 32) {
            bf16x8 af  = *(const bf16x8*)&v2l[l16 * WPITCH + k0 + quad * 8];
            bf16x8 bf0 = *(const bf16x8*)&Wl[(n0 + l16) * WPITCH + k0 + quad * 8];
            bf16x8 bf1 = *(const bf16x8*)&Wl[(n0 + 16 + l16) * WPITCH + k0 + quad * 8];
            acc0 = __builtin_amdgcn_mfma_f32_16x16x32_bf16(af, bf0, acc0, 0, 0, 0);
            acc1 = __builtin_amdgcn_mfma_f32_16x16x32_bf16(af, bf1, acc1, 0, 0, 0);
        }

        float pss[4];
        #pragma unroll
        for (int r = 0; r < 4; ++r) {
            float vsum = acc0[r]*acc0[r] + acc1[r]*acc1[r];
            vsum += __shfl_xor(vsum, 1);
            vsum += __shfl_xor(vsum, 2);
            vsum += __shfl_xor(vsum, 4);
            vsum += __shfl_xor(vsum, 8);
            pss[r] = vsum;
        }
        if (l16 == 0) {
            #pragma unroll
            for (int r = 0; r < 4; ++r) outss[quad * 4 + r][wave] = pss[r];
        }
        __syncthreads();
        if (tid < 16) {
            float on  = sqrtf(outss[tid][0] + outss[tid][1] + outss[tid][2] + outss[tid][3]);
            float onc = fmaxf(on, EPSF);
            gscale[tid] = tanhf(sc * onc) / (sc * onc);
        }
        __syncthreads();
        #pragma unroll
        for (int r = 0; r < 4; ++r) {
            int row = quad * 4 + r;
            float g = gscale[row];
            size_t base = (size_t)(row0 + row) * 128;
            out[base + n0 + l16]      = g * acc0[r];
            out[base + n0 + 16 + l16] = g * acc1[r];
        }
        __syncthreads();
    }
}

extern "C" void kernel_launch(void* const* d_in, const int* in_sizes, int n_in,
                              void* d_out, int out_size, void* d_ws, size_t ws_size,
                              hipStream_t stream) {
    const float* x     = (const float*)d_in[0];
    const int*   eidx  = (const int*)d_in[1];
    const float* c_ptr = (const float*)d_in[2];
    const float* W     = (const float*)d_in[4];
    const float* bias  = (const float*)d_in[5];
    float* out = (float*)d_out;

    int N = in_sizes[0] / 128;
    int E = in_sizes[1] / 2;

    float* v         = (float*)d_ws;                    // N*128 floats
    float* v_agg     = v + (size_t)N * 128;             // N*128 floats
    int*   deg       = (int*)(v_agg + (size_t)N * 128); // N ints
    int*   offsets   = deg + N;                         // N ints (becomes cursor)
    int*   blocksums = offsets + N;                     // SCAN_BLOCKS ints
    int*   sorted_src = blocksums + 256;                // E ints

    hipMemsetAsync(deg, 0, (size_t)N * sizeof(int), stream);

    {
        long long threads = (long long)N * 32;
        int blocks = (int)((threads + 255) / 256);
        hipLaunchKernelGGL(logmap_kernel, dim3(blocks), dim3(256), 0, stream,
                           x, c_ptr, v, N);
    }
    {
        int blocks = (E + 255) / 256;
        hipLaunchKernelGGL(hist_kernel, dim3(blocks), dim3(256), 0, stream,
                           eidx, deg, E);
    }
    hipLaunchKernelGGL(scan_pass1, dim3(SCAN_BLOCKS), dim3(256), 0, stream,
                       deg, blocksums, N);
    hipLaunchKernelGGL(scan_pass2, dim3(1), dim3(256), 0, stream,
                       blocksums, SCAN_BLOCKS);
    hipLaunchKernelGGL(scan_pass3, dim3(SCAN_BLOCKS), dim3(256), 0, stream,
                       deg, blocksums, offsets, N);
    {
        int blocks = (E + 255) / 256;
        hipLaunchKernelGGL(scatter_kernel, dim3(blocks), dim3(256), 0, stream,
                           eidx, offsets, sorted_src, E);
    }
    {
        long long threads = (long long)N * 32;
        int blocks = (int)((threads + 255) / 256);
        hipLaunchKernelGGL(gather_kernel, dim3(blocks), dim3(256), 0, stream,
                           v, sorted_src, offsets, deg, v_agg, N);
    }
    {
        const int TPB = 5;
        int numTiles = (N + 15) / 16;
        int blocks = (numTiles + TPB - 1) / TPB;
        hipLaunchKernelGGL(epilogue_mfma_kernel, dim3(blocks), dim3(256), 0, stream,
                           v_agg, W, bias, c_ptr, out, N, TPB);
    }
}

// Round 5
// 338.002 us; speedup vs baseline: 9.5683x; 1.2853x over previous
//
#include <hip/hip_runtime.h>
#include <math.h>

#define EPSF 1e-7f
#define YMAXF 0.99999f   // fp32(1 - 1e-5), same rounding as jnp clip constant
#define WPITCH 136       // bf16 pitch: 272 B/row -> start bank 4*row%32, <=2-way (free)

#define NBUCK 256        // dst buckets: bucket = dst >> 9 (needs N <= 131072)
#define PB_CHUNK 2048    // edges per bucket_scatter block

typedef short bf16x8 __attribute__((ext_vector_type(8)));
typedef short bf16x4 __attribute__((ext_vector_type(4)));
typedef float f32x4  __attribute__((ext_vector_type(4)));

__device__ __forceinline__ float grp32_sum(float v) {
    v += __shfl_xor(v, 1);
    v += __shfl_xor(v, 2);
    v += __shfl_xor(v, 4);
    v += __shfl_xor(v, 8);
    v += __shfl_xor(v, 16);
    return v;
}

__device__ __forceinline__ short f2bf(float f) {
    unsigned u = __float_as_uint(f);
    unsigned r = (u + 0x7FFFu + ((u >> 16) & 1u)) >> 16;
    return (short)r;
}

// Kernel 1: v = log_map_zero(x)
__global__ void logmap_kernel(const float* __restrict__ x,
                              const float* __restrict__ c_ptr,
                              float* __restrict__ v,
                              int N) {
    int gid = blockIdx.x * blockDim.x + threadIdx.x;
    int row = gid >> 5;
    if (row >= N) return;
    int lane = gid & 31;
    const float4 xv = ((const float4*)x)[(size_t)row * 32 + lane];
    float ss = xv.x * xv.x + xv.y * xv.y + xv.z * xv.z + xv.w * xv.w;
    ss = grp32_sum(ss);
    float sc = sqrtf(c_ptr[0]);
    float xn = fmaxf(sqrtf(ss), EPSF);
    float y = fminf(sc * xn, YMAXF);
    float s = atanhf(y) / (sc * xn);
    ((float4*)v)[(size_t)row * 32 + lane] =
        make_float4(s * xv.x, s * xv.y, s * xv.z, s * xv.w);
}

// Pass A: count edges per coarse bucket (bucket = dst>>9)
__global__ __launch_bounds__(256)
void bucket_count_kernel(const int* __restrict__ eidx_dst,
                         int* __restrict__ bucketCount, int E) {
    __shared__ int h[NBUCK];
    int tid = threadIdx.x;
    h[tid] = 0;
    __syncthreads();
    int per = (E + gridDim.x - 1) / gridDim.x;
    int start = blockIdx.x * per;
    int end = min(start + per, E);
    for (int i = start + tid; i < end; i += 256)
        atomicAdd(&h[eidx_dst[i] >> 9], 1);
    __syncthreads();
    if (h[tid]) atomicAdd(&bucketCount[tid], h[tid]);
}

// Scan of 256 bucket counts -> bucket_base (exclusive) and cursor copy
__global__ __launch_bounds__(256)
void bucket_scan_kernel(const int* __restrict__ bucketCount,
                        int* __restrict__ bucket_base,
                        int* __restrict__ cursor) {
    __shared__ int part[256];
    int tid = threadIdx.x;
    int val = bucketCount[tid];
    part[tid] = val;
    __syncthreads();
    for (int off = 1; off < 256; off <<= 1) {
        int t = (tid >= off) ? part[tid - off] : 0;
        __syncthreads();
        part[tid] += t;
        __syncthreads();
    }
    int excl = part[tid] - val;
    bucket_base[tid] = excl;
    cursor[tid] = excl;
}

// Pass B: partition edges into coarse buckets. Per-block LDS counting sort
// (unstable; rank from LDS atomicAdd return), one global cursor atomic per
// (block,bucket), run-grouped writes of packed (local_dst<<17)|src.
__global__ __launch_bounds__(256)
void bucket_scatter_kernel(const int* __restrict__ eidx,
                           int* __restrict__ cursor,
                           int* __restrict__ bucketed, int E) {
    __shared__ int hist[NBUCK];
    __shared__ int lstart[NBUCK];
    __shared__ int gbase[NBUCK];
    __shared__ int part[256];
    __shared__ int stage[PB_CHUNK];
    __shared__ unsigned char stageB[PB_CHUNK];

    int tid = threadIdx.x;
    int start = blockIdx.x * PB_CHUNK;
    int cnt = min(PB_CHUNK, E - start);
    hist[tid] = 0;
    __syncthreads();

    const int J = PB_CHUNK / 256;
    int myP[J], myB[J], myR[J];
    #pragma unroll
    for (int j = 0; j < J; ++j) {
        int idx = j * 256 + tid;
        myR[j] = -1;
        if (idx < cnt) {
            int e = start + idx;
            int d = eidx[E + e];
            int s = eidx[e];
            int b = d >> 9;
            myB[j] = b;
            myP[j] = ((d & 511) << 17) | s;
            myR[j] = atomicAdd(&hist[b], 1);
        }
    }
    __syncthreads();
    part[tid] = hist[tid];
    __syncthreads();
    for (int off = 1; off < 256; off <<= 1) {
        int t = (tid >= off) ? part[tid - off] : 0;
        __syncthreads();
        part[tid] += t;
        __syncthreads();
    }
    lstart[tid] = part[tid] - hist[tid];
    if (hist[tid]) gbase[tid] = atomicAdd(&cursor[tid], hist[tid]);
    __syncthreads();
    #pragma unroll
    for (int j = 0; j < J; ++j) {
        if (myR[j] >= 0) {
            int pos = lstart[myB[j]] + myR[j];
            stage[pos] = myP[j];
            stageB[pos] = (unsigned char)myB[j];
        }
    }
    __syncthreads();
    for (int i = tid; i < cnt; i += 256) {
        int b = stageB[i];
        bucketed[gbase[b] + (i - lstart[b])] = stage[i];
    }
}

// Pass C: per-bucket (512-node window) fine partition -> CSR.
// Writes offsets[node] (segment start), deg[node], sorted_src (within an
// L2-resident 32KB window per block).
__global__ __launch_bounds__(256)
void csr_kernel(const int* __restrict__ bucketed,
                const int* __restrict__ bucket_base,
                const int* __restrict__ cursor_post,
                int* __restrict__ offsets, int* __restrict__ deg,
                int* __restrict__ sorted_src, int N) {
    __shared__ int hist[512];
    __shared__ int pre[512];
    __shared__ int cur[512];
    __shared__ int part[256];
    int b = blockIdx.x;
    int tid = threadIdx.x;
    int start = bucket_base[b];
    int end = cursor_post[b];      // == start + count after pass B
    hist[tid] = 0;
    hist[tid + 256] = 0;
    __syncthreads();
    for (int i = start + tid; i < end; i += 256)
        atomicAdd(&hist[bucketed[i] >> 17], 1);
    __syncthreads();
    int a0 = hist[2 * tid], a1 = hist[2 * tid + 1];
    part[tid] = a0 + a1;
    __syncthreads();
    for (int off = 1; off < 256; off <<= 1) {
        int t = (tid >= off) ? part[tid - off] : 0;
        __syncthreads();
        part[tid] += t;
        __syncthreads();
    }
    int base2 = part[tid] - (a0 + a1);
    pre[2 * tid] = base2;
    pre[2 * tid + 1] = base2 + a0;
    cur[2 * tid] = base2;
    cur[2 * tid + 1] = base2 + a0;
    __syncthreads();
    int node0 = b << 9;
    for (int i = tid; i < 512; i += 256) {
        int node = node0 + i;
        if (node < N) { offsets[node] = start + pre[i]; deg[node] = hist[i]; }
    }
    for (int i = start + tid; i < end; i += 256) {
        int p = bucketed[i];
        int ld = p >> 17;
        int src = p & 0x1FFFF;
        int r = atomicAdd(&cur[ld], 1);
        sorted_src[start + r] = src;
    }
}

// Gather-reduce: 32-lane group per dst row, float4 per lane. Start-based offsets.
__global__ void gather_kernel(const float* __restrict__ v,
                              const int* __restrict__ sorted_src,
                              const int* __restrict__ offsets,
                              const int* __restrict__ deg,
                              float* __restrict__ v_agg,
                              int N) {
    int gid = blockIdx.x * blockDim.x + threadIdx.x;
    int row = gid >> 5;
    if (row >= N) return;
    int lane = gid & 31;
    int start = offsets[row];
    int d = deg[row];
    int end = start + d;
    const float4* vp = (const float4*)v;
    float4 acc = vp[(size_t)row * 32 + lane];
    int j = start;
    for (; j + 2 <= end; j += 2) {
        int s0 = sorted_src[j];
        int s1 = sorted_src[j + 1];
        float4 a = vp[(size_t)s0 * 32 + lane];
        float4 b = vp[(size_t)s1 * 32 + lane];
        acc.x += a.x + b.x;
        acc.y += a.y + b.y;
        acc.z += a.z + b.z;
        acc.w += a.w + b.w;
    }
    if (j < end) {
        float4 a = vp[(size_t)sorted_src[j] * 32 + lane];
        acc.x += a.x; acc.y += a.y; acc.z += a.z; acc.w += a.w;
    }
    float inv = 1.0f / (float)(d + 1);
    ((float4*)v_agg)[(size_t)row * 32 + lane] =
        make_float4(acc.x * inv, acc.y * inv, acc.z * inv, acc.w * inv);
}

// MFMA epilogue — unchanged (verified)
__global__ __launch_bounds__(256)
void epilogue_mfma_kernel(const float* __restrict__ v_agg,
                          const float* __restrict__ W,
                          const float* __restrict__ bias,
                          const float* __restrict__ c_ptr,
                          float* __restrict__ out,
                          int N, int tiles_per_block) {
    __shared__ short Wl[128 * WPITCH];
    __shared__ short v2l[16 * WPITCH];
    __shared__ float bias_s[128];
    __shared__ float ssrow[16];
    __shared__ float scale_s[16];
    __shared__ float outss[16][4];
    __shared__ float gscale[16];

    int tid = threadIdx.x;
    for (int i = tid; i < 4096; i += 256) {
        float4 w4 = ((const float4*)W)[i];
        int o = i >> 5;
        int k = (i & 31) * 4;
        bf16x4 w;
        w[0] = f2bf(w4.x); w[1] = f2bf(w4.y); w[2] = f2bf(w4.z); w[3] = f2bf(w4.w);
        *(bf16x4*)&Wl[o * WPITCH + k] = w;
    }
    if (tid < 128) bias_s[tid] = bias[tid];
    float sc = sqrtf(c_ptr[0]);
    __syncthreads();

    int wave = tid >> 6;
    int lane = tid & 63;
    int quad = lane >> 4;
    int l16  = lane & 15;
    int rowA = tid >> 5;
    int colA = (tid & 31) * 4;
    int n0 = wave * 32;
    float b0 = bias_s[n0 + l16];
    float b1 = bias_s[n0 + 16 + l16];

    for (int t = 0; t < tiles_per_block; ++t) {
        int tile = blockIdx.x * tiles_per_block + t;
        int row0 = tile * 16;
        if (row0 >= N) break;

        const float4* vp = (const float4*)v_agg + (size_t)row0 * 32;
        float4 a4 = vp[tid];
        float4 c4 = vp[tid + 256];
        float ssa = a4.x*a4.x + a4.y*a4.y + a4.z*a4.z + a4.w*a4.w;
        float ssb = c4.x*c4.x + c4.y*c4.y + c4.z*c4.z + c4.w*c4.w;
        ssa = grp32_sum(ssa);
        ssb = grp32_sum(ssb);
        if ((tid & 31) == 0) { ssrow[rowA] = ssa; ssrow[rowA + 8] = ssb; }
        __syncthreads();
        if (tid < 16) {
            float vn  = sqrtf(ssrow[tid]);
            float vnc = fmaxf(vn, EPSF);
            float th  = tanhf(sc * vnc);
            float tt  = th / (sc * vnc);
            float hn  = fmaxf(th / sc, EPSF);
            float y2  = fminf(sc * hn, YMAXF);
            float s2  = atanhf(y2) / (sc * hn);
            scale_s[tid] = s2 * tt;
        }
        __syncthreads();
        float sa = scale_s[rowA], sb = scale_s[rowA + 8];
        bf16x4 va, vb;
        va[0]=f2bf(a4.x*sa); va[1]=f2bf(a4.y*sa); va[2]=f2bf(a4.z*sa); va[3]=f2bf(a4.w*sa);
        vb[0]=f2bf(c4.x*sb); vb[1]=f2bf(c4.y*sb); vb[2]=f2bf(c4.z*sb); vb[3]=f2bf(c4.w*sb);
        *(bf16x4*)&v2l[rowA * WPITCH + colA] = va;
        *(bf16x4*)&v2l[(rowA + 8) * WPITCH + colA] = vb;
        __syncthreads();

        f32x4 acc0 = {b0, b0, b0, b0};
        f32x4 acc1 = {b1, b1, b1, b1};
        #pragma unroll
        for (int k0 = 0; k0 < 128; k0 += 32) {
            bf16x8 af  = *(const bf16x8*)&v2l[l16 * WPITCH + k0 + quad * 8];
            bf16x8 bf0 = *(const bf16x8*)&Wl[(n0 + l16) * WPITCH + k0 + quad * 8];
            bf16x8 bf1 = *(const bf16x8*)&Wl[(n0 + 16 + l16) * WPITCH + k0 + quad * 8];
            acc0 = __builtin_amdgcn_mfma_f32_16x16x32_bf16(af, bf0, acc0, 0, 0, 0);
            acc1 = __builtin_amdgcn_mfma_f32_16x16x32_bf16(af, bf1, acc1, 0, 0, 0);
        }

        float pss[4];
        #pragma unroll
        for (int r = 0; r < 4; ++r) {
            float vsum = acc0[r]*acc0[r] + acc1[r]*acc1[r];
            vsum += __shfl_xor(vsum, 1);
            vsum += __shfl_xor(vsum, 2);
            vsum += __shfl_xor(vsum, 4);
            vsum += __shfl_xor(vsum, 8);
            pss[r] = vsum;
        }
        if (l16 == 0) {
            #pragma unroll
            for (int r = 0; r < 4; ++r) outss[quad * 4 + r][wave] = pss[r];
        }
        __syncthreads();
        if (tid < 16) {
            float on  = sqrtf(outss[tid][0] + outss[tid][1] + outss[tid][2] + outss[tid][3]);
            float onc = fmaxf(on, EPSF);
            gscale[tid] = tanhf(sc * onc) / (sc * onc);
        }
        __syncthreads();
        #pragma unroll
        for (int r = 0; r < 4; ++r) {
            int row = quad * 4 + r;
            float g = gscale[row];
            size_t base = (size_t)(row0 + row) * 128;
            out[base + n0 + l16]      = g * acc0[r];
            out[base + n0 + 16 + l16] = g * acc1[r];
        }
        __syncthreads();
    }
}

extern "C" void kernel_launch(void* const* d_in, const int* in_sizes, int n_in,
                              void* d_out, int out_size, void* d_ws, size_t ws_size,
                              hipStream_t stream) {
    const float* x     = (const float*)d_in[0];
    const int*   eidx  = (const int*)d_in[1];
    const float* c_ptr = (const float*)d_in[2];
    const float* W     = (const float*)d_in[4];
    const float* bias  = (const float*)d_in[5];
    float* out = (float*)d_out;

    int N = in_sizes[0] / 128;
    int E = in_sizes[1] / 2;

    float* v           = (float*)d_ws;                     // N*128 floats
    float* v_agg       = v + (size_t)N * 128;              // N*128 floats
    int*   deg         = (int*)(v_agg + (size_t)N * 128);  // N
    int*   offsets     = deg + N;                          // N
    int*   bucketCount = offsets + N;                      // NBUCK
    int*   bucket_base = bucketCount + NBUCK;              // NBUCK
    int*   cursor      = bucket_base + NBUCK;              // NBUCK
    int*   bucketed    = cursor + NBUCK;                   // E (packed)
    int*   sorted_src  = bucketed + E;                     // E

    hipMemsetAsync(bucketCount, 0, NBUCK * sizeof(int), stream);

    {
        long long threads = (long long)N * 32;
        int blocks = (int)((threads + 255) / 256);
        hipLaunchKernelGGL(logmap_kernel, dim3(blocks), dim3(256), 0, stream,
                           x, c_ptr, v, N);
    }
    hipLaunchKernelGGL(bucket_count_kernel, dim3(256), dim3(256), 0, stream,
                       eidx + E, bucketCount, E);
    hipLaunchKernelGGL(bucket_scan_kernel, dim3(1), dim3(256), 0, stream,
                       bucketCount, bucket_base, cursor);
    {
        int blocks = (E + PB_CHUNK - 1) / PB_CHUNK;
        hipLaunchKernelGGL(bucket_scatter_kernel, dim3(blocks), dim3(256), 0, stream,
                           eidx, cursor, bucketed, E);
    }
    {
        int blocks = (N + 511) / 512;
        hipLaunchKernelGGL(csr_kernel, dim3(blocks), dim3(256), 0, stream,
                           bucketed, bucket_base, cursor, offsets, deg, sorted_src, N);
    }
    {
        long long threads = (long long)N * 32;
        int blocks = (int)((threads + 255) / 256);
        hipLaunchKernelGGL(gather_kernel, dim3(blocks), dim3(256), 0, stream,
                           v, sorted_src, offsets, deg, v_agg, N);
    }
    {
        const int TPB = 5;
        int numTiles = (N + 15) / 16;
        int blocks = (numTiles + TPB - 1) / TPB;
        hipLaunchKernelGGL(epilogue_mfma_kernel, dim3(blocks), dim3(256), 0, stream,
                           v_agg, W, bias, c_ptr, out, N, TPB);
    }
}

// Round 6
// 312.390 us; speedup vs baseline: 10.3527x; 1.0820x over previous
//
#include <hip/hip_runtime.h>
#include <math.h>

#define EPSF 1e-7f
#define YMAXF 0.99999f   // fp32(1 - 1e-5), same rounding as jnp clip constant
#define WPITCH 136       // bf16 pitch: 272 B/row -> <=2-way bank alias (free)

#define NBUCK 256        // dst buckets: bucket = dst >> 9 (needs N <= 131072)
#define PB_CHUNK 2048    // edges per bucket_scatter block

typedef short bf16x8 __attribute__((ext_vector_type(8)));
typedef short bf16x4 __attribute__((ext_vector_type(4)));
typedef float f32x4  __attribute__((ext_vector_type(4)));

__device__ __forceinline__ float grp32_sum(float v) {
    v += __shfl_xor(v, 1);
    v += __shfl_xor(v, 2);
    v += __shfl_xor(v, 4);
    v += __shfl_xor(v, 8);
    v += __shfl_xor(v, 16);
    return v;
}

__device__ __forceinline__ short f2bf(float f) {
    unsigned u = __float_as_uint(f);
    unsigned r = (u + 0x7FFFu + ((u >> 16) & 1u)) >> 16;
    return (short)r;
}

__device__ __forceinline__ float bf2f(short u) {
    return __uint_as_float(((unsigned)(unsigned short)u) << 16);
}

// Kernel 1: v = log_map_zero(x), stored bf16 (halves gather-side bytes)
__global__ void logmap_kernel(const float* __restrict__ x,
                              const float* __restrict__ c_ptr,
                              short* __restrict__ v_bf,
                              int N) {
    int gid = blockIdx.x * blockDim.x + threadIdx.x;
    int row = gid >> 5;
    if (row >= N) return;
    int lane = gid & 31;
    const float4 xv = ((const float4*)x)[(size_t)row * 32 + lane];
    float ss = xv.x * xv.x + xv.y * xv.y + xv.z * xv.z + xv.w * xv.w;
    ss = grp32_sum(ss);
    float sc = sqrtf(c_ptr[0]);
    float xn = fmaxf(sqrtf(ss), EPSF);
    float y = fminf(sc * xn, YMAXF);
    float s = atanhf(y) / (sc * xn);
    bf16x4 pk;
    pk[0] = f2bf(s * xv.x); pk[1] = f2bf(s * xv.y);
    pk[2] = f2bf(s * xv.z); pk[3] = f2bf(s * xv.w);
    *(bf16x4*)&v_bf[(size_t)row * 128 + lane * 4] = pk;
}

// Pass A: count edges per coarse bucket (bucket = dst>>9)
__global__ __launch_bounds__(256)
void bucket_count_kernel(const int* __restrict__ eidx_dst,
                         int* __restrict__ bucketCount, int E) {
    __shared__ int h[NBUCK];
    int tid = threadIdx.x;
    h[tid] = 0;
    __syncthreads();
    int per = (E + gridDim.x - 1) / gridDim.x;
    int start = blockIdx.x * per;
    int end = min(start + per, E);
    for (int i = start + tid; i < end; i += 256)
        atomicAdd(&h[eidx_dst[i] >> 9], 1);
    __syncthreads();
    if (h[tid]) atomicAdd(&bucketCount[tid], h[tid]);
}

// Scan of 256 bucket counts -> bucket_base (exclusive) and cursor copy
__global__ __launch_bounds__(256)
void bucket_scan_kernel(const int* __restrict__ bucketCount,
                        int* __restrict__ bucket_base,
                        int* __restrict__ cursor) {
    __shared__ int part[256];
    int tid = threadIdx.x;
    int val = bucketCount[tid];
    part[tid] = val;
    __syncthreads();
    for (int off = 1; off < 256; off <<= 1) {
        int t = (tid >= off) ? part[tid - off] : 0;
        __syncthreads();
        part[tid] += t;
        __syncthreads();
    }
    int excl = part[tid] - val;
    bucket_base[tid] = excl;
    cursor[tid] = excl;
}

// Pass B: partition edges into coarse buckets (LDS counting sort, run-grouped writes)
__global__ __launch_bounds__(256)
void bucket_scatter_kernel(const int* __restrict__ eidx,
                           int* __restrict__ cursor,
                           int* __restrict__ bucketed, int E) {
    __shared__ int hist[NBUCK];
    __shared__ int lstart[NBUCK];
    __shared__ int gbase[NBUCK];
    __shared__ int part[256];
    __shared__ int stage[PB_CHUNK];
    __shared__ unsigned char stageB[PB_CHUNK];

    int tid = threadIdx.x;
    int start = blockIdx.x * PB_CHUNK;
    int cnt = min(PB_CHUNK, E - start);
    hist[tid] = 0;
    __syncthreads();

    const int J = PB_CHUNK / 256;
    int myP[J], myB[J], myR[J];
    #pragma unroll
    for (int j = 0; j < J; ++j) {
        int idx = j * 256 + tid;
        myR[j] = -1;
        if (idx < cnt) {
            int e = start + idx;
            int d = eidx[E + e];
            int s = eidx[e];
            int b = d >> 9;
            myB[j] = b;
            myP[j] = ((d & 511) << 17) | s;
            myR[j] = atomicAdd(&hist[b], 1);
        }
    }
    __syncthreads();
    part[tid] = hist[tid];
    __syncthreads();
    for (int off = 1; off < 256; off <<= 1) {
        int t = (tid >= off) ? part[tid - off] : 0;
        __syncthreads();
        part[tid] += t;
        __syncthreads();
    }
    lstart[tid] = part[tid] - hist[tid];
    if (hist[tid]) gbase[tid] = atomicAdd(&cursor[tid], hist[tid]);
    __syncthreads();
    #pragma unroll
    for (int j = 0; j < J; ++j) {
        if (myR[j] >= 0) {
            int pos = lstart[myB[j]] + myR[j];
            stage[pos] = myP[j];
            stageB[pos] = (unsigned char)myB[j];
        }
    }
    __syncthreads();
    for (int i = tid; i < cnt; i += 256) {
        int b = stageB[i];
        bucketed[gbase[b] + (i - lstart[b])] = stage[i];
    }
}

// Pass C: per-bucket fine partition -> CSR (offsets = segment start, deg)
__global__ __launch_bounds__(256)
void csr_kernel(const int* __restrict__ bucketed,
                const int* __restrict__ bucket_base,
                const int* __restrict__ cursor_post,
                int* __restrict__ offsets, int* __restrict__ deg,
                int* __restrict__ sorted_src, int N) {
    __shared__ int hist[512];
    __shared__ int pre[512];
    __shared__ int cur[512];
    __shared__ int part[256];
    int b = blockIdx.x;
    int tid = threadIdx.x;
    int start = bucket_base[b];
    int end = cursor_post[b];
    hist[tid] = 0;
    hist[tid + 256] = 0;
    __syncthreads();
    for (int i = start + tid; i < end; i += 256)
        atomicAdd(&hist[bucketed[i] >> 17], 1);
    __syncthreads();
    int a0 = hist[2 * tid], a1 = hist[2 * tid + 1];
    part[tid] = a0 + a1;
    __syncthreads();
    for (int off = 1; off < 256; off <<= 1) {
        int t = (tid >= off) ? part[tid - off] : 0;
        __syncthreads();
        part[tid] += t;
        __syncthreads();
    }
    int base2 = part[tid] - (a0 + a1);
    pre[2 * tid] = base2;
    pre[2 * tid + 1] = base2 + a0;
    cur[2 * tid] = base2;
    cur[2 * tid + 1] = base2 + a0;
    __syncthreads();
    int node0 = b << 9;
    for (int i = tid; i < 512; i += 256) {
        int node = node0 + i;
        if (node < N) { offsets[node] = start + pre[i]; deg[node] = hist[i]; }
    }
    for (int i = start + tid; i < end; i += 256) {
        int p = bucketed[i];
        int ld = p >> 17;
        int src = p & 0x1FFFF;
        int r = atomicAdd(&cur[ld], 1);
        sorted_src[start + r] = src;
    }
}

// Fused gather + MFMA epilogue. 256 threads = 16 groups of 16 lanes; each group
// gathers one dst row (bf16 v rows, fp32 accum), computes the exp/log-map scale
// in-register, writes bf16 v2 A-fragments to LDS; then 4 waves x 2 col-tiles of
// mfma_f32_16x16x32_bf16 (+ bias, out-norm, exp_map store).
__global__ __launch_bounds__(256)
void gather_epilogue_kernel(const short* __restrict__ v_bf,
                            const int* __restrict__ sorted_src,
                            const int* __restrict__ offsets,
                            const int* __restrict__ deg,
                            const float* __restrict__ W,
                            const float* __restrict__ bias,
                            const float* __restrict__ c_ptr,
                            float* __restrict__ out,
                            int N, int tiles_per_block) {
    __shared__ short Wl[128 * WPITCH];
    __shared__ short v2l[16 * WPITCH];
    __shared__ float bias_s[128];
    __shared__ float outss[16][4];
    __shared__ float gscale[16];

    int tid = threadIdx.x;
    for (int i = tid; i < 4096; i += 256) {
        float4 w4 = ((const float4*)W)[i];
        int o = i >> 5;
        int k = (i & 31) * 4;
        bf16x4 w;
        w[0] = f2bf(w4.x); w[1] = f2bf(w4.y); w[2] = f2bf(w4.z); w[3] = f2bf(w4.w);
        *(bf16x4*)&Wl[o * WPITCH + k] = w;
    }
    if (tid < 128) bias_s[tid] = bias[tid];
    float sc = sqrtf(c_ptr[0]);
    __syncthreads();

    int wave = tid >> 6;
    int lane = tid & 63;
    int quad = lane >> 4;
    int l16  = lane & 15;
    int g  = tid >> 4;        // gather group = row in tile (0..15)
    int gl = tid & 15;        // lane in group
    int n0 = wave * 32;
    float b0 = bias_s[n0 + l16];
    float b1 = bias_s[n0 + 16 + l16];

    for (int t = 0; t < tiles_per_block; ++t) {
        int row0 = (blockIdx.x * tiles_per_block + t) * 16;
        if (row0 >= N) break;
        int row = row0 + g;
        bool valid = (row < N);

        // ---- gather phase: acc = (v[row] + sum v[src]) fp32, 8 elems/lane ----
        float acc[8];
        #pragma unroll
        for (int i = 0; i < 8; ++i) acc[i] = 0.0f;
        int start = 0, d = 0;
        if (valid) {
            start = offsets[row];
            d = deg[row];
            bf16x8 r0 = *(const bf16x8*)&v_bf[(size_t)row * 128 + gl * 8];
            #pragma unroll
            for (int i = 0; i < 8; ++i) acc[i] = bf2f(r0[i]);
        }
        for (int j = 0; j < d; j += 16) {
            int idx = j + gl;
            int batch = (idx < d) ? sorted_src[start + idx] : 0;
            int m = min(16, d - j);
            for (int jj = 0; jj < m; ++jj) {
                int src = __shfl(batch, (lane & 48) | jj);
                bf16x8 r = *(const bf16x8*)&v_bf[(size_t)src * 128 + gl * 8];
                #pragma unroll
                for (int i = 0; i < 8; ++i) acc[i] += bf2f(r[i]);
            }
        }
        float inv = 1.0f / (float)(d + 1);
        #pragma unroll
        for (int i = 0; i < 8; ++i) acc[i] *= inv;

        // row sumsq across the 16-lane group
        float ss = 0.0f;
        #pragma unroll
        for (int i = 0; i < 8; ++i) ss += acc[i] * acc[i];
        ss += __shfl_xor(ss, 1);
        ss += __shfl_xor(ss, 2);
        ss += __shfl_xor(ss, 4);
        ss += __shfl_xor(ss, 8);

        // exp_map_zero then log_map_zero scale (redundant per lane)
        float vn  = sqrtf(ss);
        float vnc = fmaxf(vn, EPSF);
        float th  = tanhf(sc * vnc);
        float tt  = th / (sc * vnc);          // x_hyp = tt * v_agg
        float hn  = fmaxf(th / sc, EPSF);
        float y2  = fminf(sc * hn, YMAXF);
        float s2  = atanhf(y2) / (sc * hn);   // v2 = s2 * x_hyp
        float scale = s2 * tt;

        bf16x8 pk;
        #pragma unroll
        for (int i = 0; i < 8; ++i) pk[i] = f2bf(acc[i] * scale);
        *(bf16x8*)&v2l[g * WPITCH + gl * 8] = pk;
        __syncthreads();

        // ---- MFMA phase ----
        f32x4 acc0 = {b0, b0, b0, b0};
        f32x4 acc1 = {b1, b1, b1, b1};
        #pragma unroll
        for (int k0 = 0; k0 < 128; k0 += 32) {
            bf16x8 af  = *(const bf16x8*)&v2l[l16 * WPITCH + k0 + quad * 8];
            bf16x8 bf0 = *(const bf16x8*)&Wl[(n0 + l16) * WPITCH + k0 + quad * 8];
            bf16x8 bf1 = *(const bf16x8*)&Wl[(n0 + 16 + l16) * WPITCH + k0 + quad * 8];
            acc0 = __builtin_amdgcn_mfma_f32_16x16x32_bf16(af, bf0, acc0, 0, 0, 0);
            acc1 = __builtin_amdgcn_mfma_f32_16x16x32_bf16(af, bf1, acc1, 0, 0, 0);
        }

        // out row sumsq: D(row=quad*4+r, col=l16)
        float pss[4];
        #pragma unroll
        for (int r = 0; r < 4; ++r) {
            float vsum = acc0[r]*acc0[r] + acc1[r]*acc1[r];
            vsum += __shfl_xor(vsum, 1);
            vsum += __shfl_xor(vsum, 2);
            vsum += __shfl_xor(vsum, 4);
            vsum += __shfl_xor(vsum, 8);
            pss[r] = vsum;
        }
        if (l16 == 0) {
            #pragma unroll
            for (int r = 0; r < 4; ++r) outss[quad * 4 + r][wave] = pss[r];
        }
        __syncthreads();
        if (tid < 16) {
            float on  = sqrtf(outss[tid][0] + outss[tid][1] + outss[tid][2] + outss[tid][3]);
            float onc = fmaxf(on, EPSF);
            gscale[tid] = tanhf(sc * onc) / (sc * onc);
        }
        __syncthreads();
        #pragma unroll
        for (int r = 0; r < 4; ++r) {
            int orow = quad * 4 + r;
            if (row0 + orow < N) {
                float gsc = gscale[orow];
                size_t base = (size_t)(row0 + orow) * 128;
                out[base + n0 + l16]      = gsc * acc0[r];
                out[base + n0 + 16 + l16] = gsc * acc1[r];
            }
        }
        __syncthreads();   // protect v2l/outss/gscale reuse next tile
    }
}

extern "C" void kernel_launch(void* const* d_in, const int* in_sizes, int n_in,
                              void* d_out, int out_size, void* d_ws, size_t ws_size,
                              hipStream_t stream) {
    const float* x     = (const float*)d_in[0];
    const int*   eidx  = (const int*)d_in[1];
    const float* c_ptr = (const float*)d_in[2];
    const float* W     = (const float*)d_in[4];
    const float* bias  = (const float*)d_in[5];
    float* out = (float*)d_out;

    int N = in_sizes[0] / 128;
    int E = in_sizes[1] / 2;

    short* v_bf        = (short*)d_ws;                     // N*128 bf16
    int*   deg         = (int*)(v_bf + (size_t)N * 128);   // N
    int*   offsets     = deg + N;                          // N
    int*   bucketCount = offsets + N;                      // NBUCK
    int*   bucket_base = bucketCount + NBUCK;              // NBUCK
    int*   cursor      = bucket_base + NBUCK;              // NBUCK
    int*   bucketed    = cursor + NBUCK;                   // E (packed)
    int*   sorted_src  = bucketed + E;                     // E

    hipMemsetAsync(bucketCount, 0, NBUCK * sizeof(int), stream);

    {
        long long threads = (long long)N * 32;
        int blocks = (int)((threads + 255) / 256);
        hipLaunchKernelGGL(logmap_kernel, dim3(blocks), dim3(256), 0, stream,
                           x, c_ptr, v_bf, N);
    }
    hipLaunchKernelGGL(bucket_count_kernel, dim3(256), dim3(256), 0, stream,
                       eidx + E, bucketCount, E);
    hipLaunchKernelGGL(bucket_scan_kernel, dim3(1), dim3(256), 0, stream,
                       bucketCount, bucket_base, cursor);
    {
        int blocks = (E + PB_CHUNK - 1) / PB_CHUNK;
        hipLaunchKernelGGL(bucket_scatter_kernel, dim3(blocks), dim3(256), 0, stream,
                           eidx, cursor, bucketed, E);
    }
    {
        int blocks = (N + 511) / 512;
        hipLaunchKernelGGL(csr_kernel, dim3(blocks), dim3(256), 0, stream,
                           bucketed, bucket_base, cursor, offsets, deg, sorted_src, N);
    }
    {
        const int TPB = 5;
        int numTiles = (N + 15) / 16;
        int blocks = (numTiles + TPB - 1) / TPB;
        hipLaunchKernelGGL(gather_epilogue_kernel, dim3(blocks), dim3(256), 0, stream,
                           v_bf, sorted_src, offsets, deg, W, bias, c_ptr, out, N, TPB);
    }
}